// Round 1
// baseline (803.063 us; speedup 1.0000x reference)
//
#include <hip/hip_runtime.h>
#include <hip/hip_bf16.h>

#define NN 20000
#define IN 128
#define HH 2
#define DD 32
#define HD 64
#define KK 3
#define RR 5
#define EE 320000
#define NEG 0.2f

// ---------------------------------------------------------------------------
// K1: projection GEMM. Block = 256 threads handles (relation r, 64-node tile).
// Computes x = h@fc_w (stored as hop 0) and res = h@res_w, 128 output cols.
// Thread (ng,cg): 4 nodes x 8 cols register tile.
// ---------------------------------------------------------------------------
__global__ __launch_bounds__(256) void proj_kernel(
    const float* __restrict__ h, const float* __restrict__ fcw,
    const float* __restrict__ resw, float* __restrict__ hops,
    float* __restrict__ res)
{
    __shared__ float hT[IN * 68];   // transposed h tile, stride 68 (16B-aligned, conflict-free)
    int bx = blockIdx.x;
    int r = bx / 313;
    int tile = bx - r * 313;
    int n0 = tile * 64;
    int tid = threadIdx.x;
    int lane = tid & 63;
    int wv = tid >> 6;

    // stage h[n0..n0+63][0..127] transposed into LDS
    int node = n0 + lane;
    #pragma unroll
    for (int j = 0; j < 32; j++) {
        int kk = wv * 32 + j;
        float v = (node < NN) ? h[node * IN + kk] : 0.f;
        hT[kk * 68 + lane] = v;   // consecutive lanes -> consecutive LDS addrs
    }
    __syncthreads();

    int cg = tid & 15;      // col group: 8 cols each (0..7 -> fc, 8..15 -> res)
    int ng = tid >> 4;      // node group: 4 nodes each
    const float* wbase = (cg < 8) ? (fcw + r * IN * HD + cg * 8)
                                  : (resw + r * IN * HD + (cg - 8) * 8);
    float acc[4][8];
    #pragma unroll
    for (int i = 0; i < 4; i++)
        #pragma unroll
        for (int j = 0; j < 8; j++) acc[i][j] = 0.f;

    #pragma unroll 2
    for (int k = 0; k < IN; k++) {
        float4 hv = *(const float4*)&hT[k * 68 + ng * 4];
        const float* wr = wbase + k * HD;
        float4 w0 = *(const float4*)wr;
        float4 w1 = *(const float4*)(wr + 4);
        float hvv[4] = {hv.x, hv.y, hv.z, hv.w};
        float wvv[8] = {w0.x, w0.y, w0.z, w0.w, w1.x, w1.y, w1.z, w1.w};
        #pragma unroll
        for (int i = 0; i < 4; i++)
            #pragma unroll
            for (int j = 0; j < 8; j++) acc[i][j] += hvv[i] * wvv[j];
    }

    #pragma unroll
    for (int i = 0; i < 4; i++) {
        int n2 = n0 + ng * 4 + i;
        if (n2 >= NN) continue;
        float4 a = {acc[i][0], acc[i][1], acc[i][2], acc[i][3]};
        float4 b = {acc[i][4], acc[i][5], acc[i][6], acc[i][7]};
        if (cg < 8) {
            float* dst = hops + ((size_t)(r * 4) * NN + n2) * HD + cg * 8;
            *(float4*)dst = a; *(float4*)(dst + 4) = b;
        } else {
            float* dst = res + ((size_t)r * NN + n2) * HD + (cg - 8) * 8;
            *(float4*)dst = a; *(float4*)(dst + 4) = b;
        }
    }
}

// ---------------------------------------------------------------------------
// K1b: per-node attention scalars el/er. Thread per (r,n,h).
// ---------------------------------------------------------------------------
__global__ __launch_bounds__(256) void attn_node_kernel(
    const float* __restrict__ hops, const float* __restrict__ attn_l,
    const float* __restrict__ attn_r, float* __restrict__ el,
    float* __restrict__ er)
{
    int idx = blockIdx.x * 256 + threadIdx.x;
    if (idx >= RR * NN * HH) return;
    int h_ = idx & 1;
    int n = (idx >> 1) % NN;
    int r = idx / (NN * HH);
    const float* x = hops + ((size_t)(r * 4) * NN + n) * HD + h_ * DD;
    const float* al = attn_l + (r * HH + h_) * DD;
    const float* ar = attn_r + (r * HH + h_) * DD;
    float sl = 0.f, sr = 0.f;
    #pragma unroll
    for (int d = 0; d < DD; d++) { float v = x[d]; sl += v * al[d]; sr += v * ar[d]; }
    el[idx] = sl;
    er[idx] = sr;
}

// ---------------------------------------------------------------------------
// K2: histogram of dst per relation
// ---------------------------------------------------------------------------
__global__ __launch_bounds__(256) void count_kernel(
    const int* __restrict__ dst, int* __restrict__ counts)
{
    int idx = blockIdx.x * 256 + threadIdx.x;
    if (idx >= RR * EE) return;
    int r = idx / EE;
    atomicAdd(&counts[r * NN + dst[idx]], 1);
}

// ---------------------------------------------------------------------------
// K3: per-relation exclusive scan -> row_ptr + cursor copy. 1 block per r.
// ---------------------------------------------------------------------------
__global__ __launch_bounds__(256) void scan_kernel(
    const int* __restrict__ counts, int* __restrict__ rowp,
    int* __restrict__ cursor)
{
    __shared__ int s[256];
    __shared__ int carry;
    int r = blockIdx.x;
    int tid = threadIdx.x;
    if (tid == 0) { carry = 0; rowp[r * (NN + 1)] = 0; }
    __syncthreads();
    const int* c = counts + r * NN;
    int* rp = rowp + r * (NN + 1);
    int* cur = cursor + r * NN;
    for (int base = 0; base < NN; base += 256) {
        int i = base + tid;
        int v = (i < NN) ? c[i] : 0;
        s[tid] = v;
        __syncthreads();
        for (int off = 1; off < 256; off <<= 1) {
            int t = (tid >= off) ? s[tid - off] : 0;
            __syncthreads();
            s[tid] += t;
            __syncthreads();
        }
        int incl = s[tid];
        if (i < NN) { rp[i + 1] = carry + incl; cur[i] = carry + incl - v; }
        __syncthreads();
        if (tid == 255) carry += incl;
        __syncthreads();
    }
}

// ---------------------------------------------------------------------------
// K4: scatter edges into CSR slots + compute leaky logits
// ---------------------------------------------------------------------------
__global__ __launch_bounds__(256) void scatter_kernel(
    const int* __restrict__ src, const int* __restrict__ dst,
    const float* __restrict__ el, const float* __restrict__ er,
    int* __restrict__ cursor, int* __restrict__ csrS, float* __restrict__ csrA)
{
    int idx = blockIdx.x * 256 + threadIdx.x;
    if (idx >= RR * EE) return;
    int r = idx / EE;
    int s = src[idx], d = dst[idx];
    float l0 = el[(r * NN + s) * 2] + er[(r * NN + d) * 2];
    float l1 = el[(r * NN + s) * 2 + 1] + er[(r * NN + d) * 2 + 1];
    l0 = l0 > 0.f ? l0 : NEG * l0;
    l1 = l1 > 0.f ? l1 : NEG * l1;
    int pos = atomicAdd(cursor + r * NN + d, 1);
    csrS[(size_t)r * EE + pos] = s;
    float2* A = (float2*)csrA + (size_t)r * EE;
    A[pos] = make_float2(l0, l1);
}

// ---------------------------------------------------------------------------
// K5: per-dst softmax over its CSR edge segment (in place logits -> alpha)
// ---------------------------------------------------------------------------
__global__ __launch_bounds__(256) void alpha_kernel(
    float* __restrict__ csrA, const int* __restrict__ rowp)
{
    int idx = blockIdx.x * 256 + threadIdx.x;
    if (idx >= RR * NN) return;
    int r = idx / NN;
    int n = idx - r * NN;
    int b = rowp[r * (NN + 1) + n];
    int e = rowp[r * (NN + 1) + n + 1];
    if (e <= b) return;
    float2* A = (float2*)csrA + (size_t)r * EE;
    float m0 = -1e30f, m1 = -1e30f;
    for (int i = b; i < e; i++) { float2 v = A[i]; m0 = fmaxf(m0, v.x); m1 = fmaxf(m1, v.y); }
    float s0 = 0.f, s1 = 0.f;
    for (int i = b; i < e; i++) {
        float2 v = A[i];
        v.x = __expf(v.x - m0); v.y = __expf(v.y - m1);
        s0 += v.x; s1 += v.y;
        A[i] = v;
    }
    float i0 = 1.f / fmaxf(s0, 1e-9f), i1 = 1.f / fmaxf(s1, 1e-9f);
    for (int i = b; i < e; i++) { float2 v = A[i]; v.x *= i0; v.y *= i1; A[i] = v; }
}

// ---------------------------------------------------------------------------
// K6: one diffusion hop. Wave per (r, dst); lane = (h,d) element.
// ---------------------------------------------------------------------------
__global__ __launch_bounds__(256) void hop_kernel(
    float* __restrict__ hops, const int* __restrict__ csrS,
    const float* __restrict__ csrA, const int* __restrict__ rowp, int k)
{
    int w = (blockIdx.x * 256 + threadIdx.x) >> 6;
    if (w >= RR * NN) return;
    int lane = threadIdx.x & 63;
    int r = w / NN;
    int n = w - r * NN;
    int b = rowp[r * (NN + 1) + n];
    int e = rowp[r * (NN + 1) + n + 1];
    const float* hin = hops + (size_t)(r * 4 + k - 1) * NN * HD;
    const int* cs = csrS + (size_t)r * EE;
    const float* ca = csrA + (size_t)r * EE * 2 + (lane >> 5);
    float acc = 0.f, acc2 = 0.f;
    int i = b;
    for (; i + 1 < e; i += 2) {
        int s0 = cs[i], s1 = cs[i + 1];
        float a0 = ca[2 * i], a1 = ca[2 * (i + 1)];
        acc  += a0 * hin[(size_t)s0 * HD + lane];
        acc2 += a1 * hin[(size_t)s1 * HD + lane];
    }
    if (i < e) acc += ca[2 * i] * hin[(size_t)cs[i] * HD + lane];
    acc += acc2;
    hops[(size_t)(r * 4 + k) * NN * HD + (size_t)n * HD + lane] = acc;
}

// ---------------------------------------------------------------------------
// K7: hop-norm + hop attention + residual + relation combine + head mean.
// Wave per node; 32-lane shuffle reductions within each head half.
// ---------------------------------------------------------------------------
__device__ __forceinline__ float red32(float v) {
    v += __shfl_xor(v, 16, 64);
    v += __shfl_xor(v, 8, 64);
    v += __shfl_xor(v, 4, 64);
    v += __shfl_xor(v, 2, 64);
    v += __shfl_xor(v, 1, 64);
    return v;
}

__global__ __launch_bounds__(256) void final_kernel(
    const float* __restrict__ hops, const float* __restrict__ res,
    const float* __restrict__ hal, const float* __restrict__ har,
    const float* __restrict__ w_rel, const float* __restrict__ b_rel,
    float* __restrict__ out)
{
    int w = (blockIdx.x * 256 + threadIdx.x) >> 6;
    if (w >= NN) return;
    int lane = threadIdx.x & 63;
    int h_ = lane >> 5;
    int d_ = lane & 31;
    float acc = 0.f;
    #pragma unroll
    for (int r = 0; r < RR; r++) {
        float wr = b_rel[r];
        #pragma unroll
        for (int j = 0; j < RR; j++) wr += w_rel[r * RR + j];
        float halv = hal[(r * HH + h_) * DD + d_];
        float harv = har[(r * HH + h_) * DD + d_];
        float vn[4], lg[4];
        float hr = 0.f;
        #pragma unroll
        for (int kk = 0; kk < 4; kk++) {
            float v = hops[((size_t)(r * 4 + kk) * NN + w) * HD + lane];
            float sq = red32(v * v);
            float inv = 1.f / fmaxf(sqrtf(sq), 1e-9f);
            v *= inv;
            vn[kk] = v;
            lg[kk] = red32(v * halv);
            if (kk == 0) hr = red32(v * harv);
        }
        float mx = -1e30f;
        #pragma unroll
        for (int kk = 0; kk < 4; kk++) {
            float l = lg[kk] + hr;
            l = l > 0.f ? l : NEG * l;
            lg[kk] = l;
            mx = fmaxf(mx, l);
        }
        float s = 0.f;
        #pragma unroll
        for (int kk = 0; kk < 4; kk++) { float ex = __expf(lg[kk] - mx); lg[kk] = ex; s += ex; }
        float o = 0.f;
        #pragma unroll
        for (int kk = 0; kk < 4; kk++) o += lg[kk] * vn[kk];
        o /= s;
        o += res[((size_t)r * NN + w) * HD + lane];
        acc += wr * o;
    }
    float other = __shfl_xor(acc, 32, 64);
    if (lane < 32) out[(size_t)w * DD + d_] = 0.5f * (acc + other);
}

// ---------------------------------------------------------------------------
extern "C" void kernel_launch(void* const* d_in, const int* in_sizes, int n_in,
                              void* d_out, int out_size, void* d_ws, size_t ws_size,
                              hipStream_t stream) {
    (void)in_sizes; (void)n_in; (void)out_size; (void)ws_size;
    const float* h     = (const float*)d_in[0];
    const int*   src   = (const int*)d_in[1];
    const int*   dst   = (const int*)d_in[2];
    const float* fcw   = (const float*)d_in[3];
    const float* resw  = (const float*)d_in[4];
    const float* atl   = (const float*)d_in[5];
    const float* atr   = (const float*)d_in[6];
    const float* hal   = (const float*)d_in[7];
    const float* har   = (const float*)d_in[8];
    const float* wrel  = (const float*)d_in[9];
    const float* brel  = (const float*)d_in[10];
    float* out = (float*)d_out;

    float* ws = (float*)d_ws;
    size_t off = 0;
    float* hops = ws + off;  off += (size_t)RR * 4 * NN * HD;   // 25.6M
    float* res  = ws + off;  off += (size_t)RR * NN * HD;       // 6.4M
    float* el   = ws + off;  off += (size_t)RR * NN * HH;
    float* er   = ws + off;  off += (size_t)RR * NN * HH;
    float* csrA = ws + off;  off += (size_t)RR * EE * HH;
    int* csrS   = (int*)(ws + off);  off += (size_t)RR * EE;
    int* rowp   = (int*)(ws + off);  off += (size_t)RR * (NN + 1);
    int* cursor = (int*)(ws + off);  off += (size_t)RR * NN;
    int* counts = (int*)(ws + off);  off += (size_t)RR * NN;

    hipMemsetAsync(counts, 0, (size_t)RR * NN * sizeof(int), stream);

    proj_kernel<<<313 * RR, 256, 0, stream>>>(h, fcw, resw, hops, res);
    attn_node_kernel<<<(RR * NN * HH + 255) / 256, 256, 0, stream>>>(hops, atl, atr, el, er);
    count_kernel<<<(RR * EE + 255) / 256, 256, 0, stream>>>(dst, counts);
    scan_kernel<<<RR, 256, 0, stream>>>(counts, rowp, cursor);
    scatter_kernel<<<(RR * EE + 255) / 256, 256, 0, stream>>>(src, dst, el, er, cursor, csrS, csrA);
    alpha_kernel<<<(RR * NN + 255) / 256, 256, 0, stream>>>(csrA, rowp);
    hop_kernel<<<(RR * NN) / 4, 256, 0, stream>>>(hops, csrS, csrA, rowp, 1);
    hop_kernel<<<(RR * NN) / 4, 256, 0, stream>>>(hops, csrS, csrA, rowp, 2);
    hop_kernel<<<(RR * NN) / 4, 256, 0, stream>>>(hops, csrS, csrA, rowp, 3);
    final_kernel<<<NN / 4, 256, 0, stream>>>(hops, res, hal, har, wrel, brel, out);
}

// Round 2
// 789.630 us; speedup vs baseline: 1.0170x; 1.0170x over previous
//
#include <hip/hip_runtime.h>
#include <hip/hip_bf16.h>

#define NN 20000
#define IN 128
#define HH 2
#define DD 32
#define HD 64
#define KK 3
#define RR 5
#define EE 320000
#define NEG 0.2f

#define SA 132   // LDS stride for transposed A tile (16B-aligned rows)

// ---------------------------------------------------------------------------
// K1: projection GEMM, LDS-tiled. Block = (r, 128-node tile), 256 threads.
// C-tile 128 nodes x 128 cols (cols 0..63 = fc -> hops hop0, 64..127 = res).
// Thread (ty,tx): 8 nodes x (4 fc cols + 4 res cols). k staged in chunks of 32.
// ---------------------------------------------------------------------------
__global__ __launch_bounds__(256) void proj_kernel(
    const float* __restrict__ h, const float* __restrict__ fcw,
    const float* __restrict__ resw, float* __restrict__ hops,
    float* __restrict__ res)
{
    __shared__ float As[32 * SA];    // [k][node], transposed, 16.9 KB
    __shared__ float Bs[32 * 128];   // [k][col], 16.4 KB
    int bx = blockIdx.x;
    int r = bx / 157;
    int tile = bx - r * 157;
    int n0 = tile * 128;
    int tid = threadIdx.x;
    int tx = tid & 15;      // col group
    int ty = tid >> 4;      // node group (8 nodes)

    const float* fw = fcw + r * IN * HD;
    const float* rw = resw + r * IN * HD;

    float acc[8][8];
    #pragma unroll
    for (int i = 0; i < 8; i++)
        #pragma unroll
        for (int j = 0; j < 8; j++) acc[i][j] = 0.f;

    for (int kc = 0; kc < IN; kc += 32) {
        // stage A: 128 nodes x 32 k, transposed into As[k][node]
        #pragma unroll
        for (int i = 0; i < 4; i++) {
            int f = tid + 256 * i;       // float4 index in [0,1024)
            int node = f >> 3;           // 0..127
            int j = f & 7;               // which float4 of the 32-k row
            int gn = n0 + node;
            float4 v = make_float4(0.f, 0.f, 0.f, 0.f);
            if (gn < NN) v = *(const float4*)&h[gn * IN + kc + j * 4];
            As[(j * 4 + 0) * SA + node] = v.x;
            As[(j * 4 + 1) * SA + node] = v.y;
            As[(j * 4 + 2) * SA + node] = v.z;
            As[(j * 4 + 3) * SA + node] = v.w;
        }
        // stage B: 32 k x 128 cols (fc | res)
        #pragma unroll
        for (int i = 0; i < 4; i++) {
            int f = tid + 256 * i;       // float4 index in [0,1024)
            int k = f >> 5;
            int c = (f & 31) * 4;
            float4 v = (c < 64) ? *(const float4*)&fw[(kc + k) * HD + c]
                                : *(const float4*)&rw[(kc + k) * HD + (c - 64)];
            *(float4*)&Bs[k * 128 + c] = v;
        }
        __syncthreads();
        #pragma unroll
        for (int k = 0; k < 32; k++) {
            float4 a0 = *(const float4*)&As[k * SA + ty * 8];
            float4 a1 = *(const float4*)&As[k * SA + ty * 8 + 4];
            float4 b0 = *(const float4*)&Bs[k * 128 + tx * 4];        // fc cols
            float4 b1 = *(const float4*)&Bs[k * 128 + 64 + tx * 4];   // res cols
            float av[8] = {a0.x, a0.y, a0.z, a0.w, a1.x, a1.y, a1.z, a1.w};
            float bv[8] = {b0.x, b0.y, b0.z, b0.w, b1.x, b1.y, b1.z, b1.w};
            #pragma unroll
            for (int i = 0; i < 8; i++)
                #pragma unroll
                for (int j = 0; j < 8; j++) acc[i][j] += av[i] * bv[j];
        }
        __syncthreads();
    }

    #pragma unroll
    for (int i = 0; i < 8; i++) {
        int n2 = n0 + ty * 8 + i;
        if (n2 >= NN) continue;
        float4 a = {acc[i][0], acc[i][1], acc[i][2], acc[i][3]};
        float4 b = {acc[i][4], acc[i][5], acc[i][6], acc[i][7]};
        *(float4*)&hops[((size_t)(r * 4) * NN + n2) * HD + tx * 4] = a;
        *(float4*)&res[((size_t)r * NN + n2) * HD + tx * 4] = b;
    }
}

// ---------------------------------------------------------------------------
// K1b: per-node attention scalars el/er. Thread per (r,n,h).
// ---------------------------------------------------------------------------
__global__ __launch_bounds__(256) void attn_node_kernel(
    const float* __restrict__ hops, const float* __restrict__ attn_l,
    const float* __restrict__ attn_r, float* __restrict__ el,
    float* __restrict__ er)
{
    int idx = blockIdx.x * 256 + threadIdx.x;
    if (idx >= RR * NN * HH) return;
    int h_ = idx & 1;
    int n = (idx >> 1) % NN;
    int r = idx / (NN * HH);
    const float4* x = (const float4*)(hops + ((size_t)(r * 4) * NN + n) * HD + h_ * DD);
    const float4* al = (const float4*)(attn_l + (r * HH + h_) * DD);
    const float4* ar = (const float4*)(attn_r + (r * HH + h_) * DD);
    float sl = 0.f, sr = 0.f;
    #pragma unroll
    for (int d = 0; d < 8; d++) {
        float4 v = x[d], a = al[d], b = ar[d];
        sl += v.x * a.x + v.y * a.y + v.z * a.z + v.w * a.w;
        sr += v.x * b.x + v.y * b.y + v.z * b.z + v.w * b.w;
    }
    el[idx] = sl;
    er[idx] = sr;
}

// ---------------------------------------------------------------------------
// K2: histogram of dst per relation
// ---------------------------------------------------------------------------
__global__ __launch_bounds__(256) void count_kernel(
    const int* __restrict__ dst, int* __restrict__ counts)
{
    int idx = blockIdx.x * 256 + threadIdx.x;
    if (idx >= RR * EE) return;
    int r = idx / EE;
    atomicAdd(&counts[r * NN + dst[idx]], 1);
}

// ---------------------------------------------------------------------------
// K3: per-relation exclusive scan -> row_ptr + cursor copy. 1 block per r.
// ---------------------------------------------------------------------------
__global__ __launch_bounds__(256) void scan_kernel(
    const int* __restrict__ counts, int* __restrict__ rowp,
    int* __restrict__ cursor)
{
    __shared__ int s[256];
    __shared__ int carry;
    int r = blockIdx.x;
    int tid = threadIdx.x;
    if (tid == 0) { carry = 0; rowp[r * (NN + 1)] = 0; }
    __syncthreads();
    const int* c = counts + r * NN;
    int* rp = rowp + r * (NN + 1);
    int* cur = cursor + r * NN;
    for (int base = 0; base < NN; base += 256) {
        int i = base + tid;
        int v = (i < NN) ? c[i] : 0;
        s[tid] = v;
        __syncthreads();
        for (int off = 1; off < 256; off <<= 1) {
            int t = (tid >= off) ? s[tid - off] : 0;
            __syncthreads();
            s[tid] += t;
            __syncthreads();
        }
        int incl = s[tid];
        if (i < NN) { rp[i + 1] = carry + incl; cur[i] = carry + incl - v; }
        __syncthreads();
        if (tid == 255) carry += incl;
        __syncthreads();
    }
}

// ---------------------------------------------------------------------------
// K4: scatter edges into CSR slots; record = float4 {src_as_float, l0, l1, 0}
// ---------------------------------------------------------------------------
__global__ __launch_bounds__(256) void scatter_kernel(
    const int* __restrict__ src, const int* __restrict__ dst,
    const float* __restrict__ el, const float* __restrict__ er,
    int* __restrict__ cursor, float4* __restrict__ csrE)
{
    int idx = blockIdx.x * 256 + threadIdx.x;
    if (idx >= RR * EE) return;
    int r = idx / EE;
    int s = src[idx], d = dst[idx];
    float l0 = el[(r * NN + s) * 2] + er[(r * NN + d) * 2];
    float l1 = el[(r * NN + s) * 2 + 1] + er[(r * NN + d) * 2 + 1];
    l0 = l0 > 0.f ? l0 : NEG * l0;
    l1 = l1 > 0.f ? l1 : NEG * l1;
    int pos = atomicAdd(cursor + r * NN + d, 1);
    csrE[(size_t)r * EE + pos] = make_float4(__int_as_float(s), l0, l1, 0.f);
}

// ---------------------------------------------------------------------------
// K5: per-dst softmax (online max+sum, then one normalize pass)
// ---------------------------------------------------------------------------
__global__ __launch_bounds__(256) void alpha_kernel(
    float4* __restrict__ csrE, const int* __restrict__ rowp)
{
    int idx = blockIdx.x * 256 + threadIdx.x;
    if (idx >= RR * NN) return;
    int r = idx / NN;
    int n = idx - r * NN;
    int b = rowp[r * (NN + 1) + n];
    int e = rowp[r * (NN + 1) + n + 1];
    if (e <= b) return;
    float4* E = csrE + (size_t)r * EE;
    float m0 = -1e30f, m1 = -1e30f, s0 = 0.f, s1 = 0.f;
    for (int i = b; i < e; i++) {
        float4 v = E[i];
        float nm0 = fmaxf(m0, v.y);
        float nm1 = fmaxf(m1, v.z);
        s0 = s0 * __expf(m0 - nm0) + __expf(v.y - nm0);
        s1 = s1 * __expf(m1 - nm1) + __expf(v.z - nm1);
        m0 = nm0; m1 = nm1;
    }
    float i0 = 1.f / fmaxf(s0, 1e-9f), i1 = 1.f / fmaxf(s1, 1e-9f);
    for (int i = b; i < e; i++) {
        float4 v = E[i];
        v.y = __expf(v.y - m0) * i0;
        v.z = __expf(v.z - m1) * i1;
        E[i] = v;
    }
}

// ---------------------------------------------------------------------------
// K6: one diffusion hop. Wave per (r, dst); lane = feature element.
// ---------------------------------------------------------------------------
__global__ __launch_bounds__(256) void hop_kernel(
    float* __restrict__ hops, const float4* __restrict__ csrE,
    const int* __restrict__ rowp, int k)
{
    int w = (blockIdx.x * 256 + threadIdx.x) >> 6;
    if (w >= RR * NN) return;
    int lane = threadIdx.x & 63;
    int hsel = lane >> 5;
    int r = w / NN;
    int n = w - r * NN;
    int b = rowp[r * (NN + 1) + n];
    int e = rowp[r * (NN + 1) + n + 1];
    const float* hin = hops + (size_t)(r * 4 + k - 1) * NN * HD;
    const float4* E = csrE + (size_t)r * EE;
    float acc = 0.f, acc2 = 0.f;
    int i = b;
    for (; i + 1 < e; i += 2) {
        float4 e0 = E[i], e1 = E[i + 1];
        int s0 = __float_as_int(e0.x), s1 = __float_as_int(e1.x);
        float a0 = hsel ? e0.z : e0.y;
        float a1 = hsel ? e1.z : e1.y;
        acc  += a0 * hin[(size_t)s0 * HD + lane];
        acc2 += a1 * hin[(size_t)s1 * HD + lane];
    }
    if (i < e) {
        float4 e0 = E[i];
        float a0 = hsel ? e0.z : e0.y;
        acc += a0 * hin[(size_t)__float_as_int(e0.x) * HD + lane];
    }
    acc += acc2;
    hops[(size_t)(r * 4 + k) * NN * HD + (size_t)n * HD + lane] = acc;
}

// ---------------------------------------------------------------------------
// K7: hop-norm + hop attention + residual + relation combine + head mean.
// ---------------------------------------------------------------------------
__device__ __forceinline__ float red32(float v) {
    v += __shfl_xor(v, 16, 64);
    v += __shfl_xor(v, 8, 64);
    v += __shfl_xor(v, 4, 64);
    v += __shfl_xor(v, 2, 64);
    v += __shfl_xor(v, 1, 64);
    return v;
}

__global__ __launch_bounds__(256) void final_kernel(
    const float* __restrict__ hops, const float* __restrict__ res,
    const float* __restrict__ hal, const float* __restrict__ har,
    const float* __restrict__ w_rel, const float* __restrict__ b_rel,
    float* __restrict__ out)
{
    int w = (blockIdx.x * 256 + threadIdx.x) >> 6;
    if (w >= NN) return;
    int lane = threadIdx.x & 63;
    int h_ = lane >> 5;
    int d_ = lane & 31;
    float acc = 0.f;
    #pragma unroll
    for (int r = 0; r < RR; r++) {
        float wr = b_rel[r];
        #pragma unroll
        for (int j = 0; j < RR; j++) wr += w_rel[r * RR + j];
        float halv = hal[(r * HH + h_) * DD + d_];
        float harv = har[(r * HH + h_) * DD + d_];
        float vn[4], lg[4];
        float hr = 0.f;
        #pragma unroll
        for (int kk = 0; kk < 4; kk++) {
            float v = hops[((size_t)(r * 4 + kk) * NN + w) * HD + lane];
            float sq = red32(v * v);
            float inv = 1.f / fmaxf(sqrtf(sq), 1e-9f);
            v *= inv;
            vn[kk] = v;
            lg[kk] = red32(v * halv);
            if (kk == 0) hr = red32(v * harv);
        }
        float mx = -1e30f;
        #pragma unroll
        for (int kk = 0; kk < 4; kk++) {
            float l = lg[kk] + hr;
            l = l > 0.f ? l : NEG * l;
            lg[kk] = l;
            mx = fmaxf(mx, l);
        }
        float s = 0.f;
        #pragma unroll
        for (int kk = 0; kk < 4; kk++) { float ex = __expf(lg[kk] - mx); lg[kk] = ex; s += ex; }
        float o = 0.f;
        #pragma unroll
        for (int kk = 0; kk < 4; kk++) o += lg[kk] * vn[kk];
        o /= s;
        o += res[((size_t)r * NN + w) * HD + lane];
        acc += wr * o;
    }
    float other = __shfl_xor(acc, 32, 64);
    if (lane < 32) out[(size_t)w * DD + d_] = 0.5f * (acc + other);
}

// ---------------------------------------------------------------------------
extern "C" void kernel_launch(void* const* d_in, const int* in_sizes, int n_in,
                              void* d_out, int out_size, void* d_ws, size_t ws_size,
                              hipStream_t stream) {
    (void)in_sizes; (void)n_in; (void)out_size; (void)ws_size;
    const float* h     = (const float*)d_in[0];
    const int*   src   = (const int*)d_in[1];
    const int*   dst   = (const int*)d_in[2];
    const float* fcw   = (const float*)d_in[3];
    const float* resw  = (const float*)d_in[4];
    const float* atl   = (const float*)d_in[5];
    const float* atr   = (const float*)d_in[6];
    const float* hal   = (const float*)d_in[7];
    const float* har   = (const float*)d_in[8];
    const float* wrel  = (const float*)d_in[9];
    const float* brel  = (const float*)d_in[10];
    float* out = (float*)d_out;

    float* ws = (float*)d_ws;
    size_t off = 0;
    float* hops = ws + off;  off += (size_t)RR * 4 * NN * HD;   // 25.6M floats
    float* res  = ws + off;  off += (size_t)RR * NN * HD;       // 6.4M
    float* el   = ws + off;  off += (size_t)RR * NN * HH;
    float* er   = ws + off;  off += (size_t)RR * NN * HH;
    float4* csrE = (float4*)(ws + off);  off += (size_t)RR * EE * 4;  // 1.6M float4
    int* rowp   = (int*)(ws + off);  off += (size_t)RR * (NN + 1);
    int* cursor = (int*)(ws + off);  off += (size_t)RR * NN;
    int* counts = (int*)(ws + off);  off += (size_t)RR * NN;

    hipMemsetAsync(counts, 0, (size_t)RR * NN * sizeof(int), stream);

    proj_kernel<<<157 * RR, 256, 0, stream>>>(h, fcw, resw, hops, res);
    attn_node_kernel<<<(RR * NN * HH + 255) / 256, 256, 0, stream>>>(hops, atl, atr, el, er);
    count_kernel<<<(RR * EE + 255) / 256, 256, 0, stream>>>(dst, counts);
    scan_kernel<<<RR, 256, 0, stream>>>(counts, rowp, cursor);
    scatter_kernel<<<(RR * EE + 255) / 256, 256, 0, stream>>>(src, dst, el, er, cursor, csrE);
    alpha_kernel<<<(RR * NN + 255) / 256, 256, 0, stream>>>(csrE, rowp);
    hop_kernel<<<(RR * NN) / 4, 256, 0, stream>>>(hops, csrE, rowp, 1);
    hop_kernel<<<(RR * NN) / 4, 256, 0, stream>>>(hops, csrE, rowp, 2);
    hop_kernel<<<(RR * NN) / 4, 256, 0, stream>>>(hops, csrE, rowp, 3);
    final_kernel<<<NN / 4, 256, 0, stream>>>(hops, res, hal, har, wrel, brel, out);
}

// Round 3
// 573.158 us; speedup vs baseline: 1.4011x; 1.3777x over previous
//
#include <hip/hip_runtime.h>
#include <hip/hip_bf16.h>

#define NN 20000
#define IN 128
#define HH 2
#define DD 32
#define HD 64
#define KK 3
#define RR 5
#define EE 320000
#define NEG 0.2f

#define PADK 136   // LDS row stride in bf16 elems (128 + 8): +16B per row

typedef short v8s __attribute__((ext_vector_type(8)));
typedef float v4f __attribute__((ext_vector_type(4)));

__device__ __forceinline__ ushort f2b(float f) {
    unsigned u = __float_as_uint(f);
    unsigned r = (u + 0x7fff + ((u >> 16) & 1)) >> 16;   // RNE
    return (ushort)r;
}

// ---------------------------------------------------------------------------
// K0a: h (fp32) -> hb (bf16), row-major [n][k]
// ---------------------------------------------------------------------------
__global__ __launch_bounds__(256) void cvt_h_kernel(
    const float* __restrict__ h, ushort* __restrict__ hb)
{
    int i = blockIdx.x * 256 + threadIdx.x;      // float4 index
    if (i >= NN * IN / 4) return;
    float4 v = ((const float4*)h)[i];
    ushort4 o = make_ushort4(f2b(v.x), f2b(v.y), f2b(v.z), f2b(v.w));
    ((ushort4*)hb)[i] = o;
}

// ---------------------------------------------------------------------------
// K0b: weights -> wb bf16, transposed+fused: wb[r][col][k], col<64=fc, >=64=res
// ---------------------------------------------------------------------------
__global__ __launch_bounds__(256) void cvt_w_kernel(
    const float* __restrict__ fcw, const float* __restrict__ resw,
    ushort* __restrict__ wb)
{
    int i = blockIdx.x * 256 + threadIdx.x;
    if (i >= RR * 128 * IN) return;
    int k = i & 127;
    int c = (i >> 7) & 127;
    int r = i >> 14;
    float v = (c < HD) ? fcw[(r * IN + k) * HD + c] : resw[(r * IN + k) * HD + (c - HD)];
    wb[i] = f2b(v);   // i == (r*128 + c)*IN + k
}

// ---------------------------------------------------------------------------
// K1: projection via bf16 MFMA. Block = (r, 64-node tile), 256 thr = 4 waves.
// C-tile 64 nodes x 128 cols (0..63 -> hop0, 64..127 -> res), fp32 out.
// Wave w owns cols [w*32, w*32+32): 4 M-tiles x 2 N-tiles, K=128 in 4 steps.
// ---------------------------------------------------------------------------
__global__ __launch_bounds__(256) void proj_mfma(
    const ushort* __restrict__ hb, const ushort* __restrict__ wb,
    float* __restrict__ hops, float* __restrict__ res)
{
    __shared__ ushort As[64 * PADK];    // [node][k]  17.4 KB
    __shared__ ushort Bs[128 * PADK];   // [col][k]   34.8 KB
    int bx = blockIdx.x;
    int r = bx / 313;
    int tile = bx - r * 313;
    int n0 = tile * 64;
    int tid = threadIdx.x;

    // stage A: 64 rows x 128 k = 1024 16B-chunks / 256 thr = 4 each
    #pragma unroll
    for (int i = 0; i < 4; i++) {
        int c = tid + 256 * i;
        int row = c >> 4;            // 16 chunks per row
        int off = (c & 15) * 8;
        int gn = n0 + row;
        uint4 v = make_uint4(0, 0, 0, 0);
        if (gn < NN) v = *(const uint4*)&hb[gn * IN + off];
        *(uint4*)&As[row * PADK + off] = v;
    }
    // stage B: 128 cols x 128 k = 2048 chunks / 256 = 8 each
    const ushort* wr = wb + (size_t)r * 128 * IN;
    #pragma unroll
    for (int i = 0; i < 8; i++) {
        int c = tid + 256 * i;
        int row = c >> 4;
        int off = (c & 15) * 8;
        *(uint4*)&Bs[row * PADK + off] = *(const uint4*)&wr[row * IN + off];
    }
    __syncthreads();

    int w = tid >> 6, lane = tid & 63;
    int lm = lane & 15, lq = lane >> 4;

    v4f acc[4][2];
    #pragma unroll
    for (int mt = 0; mt < 4; mt++)
        #pragma unroll
        for (int nt = 0; nt < 2; nt++) acc[mt][nt] = (v4f){0.f, 0.f, 0.f, 0.f};

    const ushort* Ab = &As[lm * PADK + lq * 8];
    const ushort* Bb = &Bs[(w * 32 + lm) * PADK + lq * 8];

    #pragma unroll
    for (int ks = 0; ks < 4; ks++) {
        v8s a[4], b[2];
        #pragma unroll
        for (int mt = 0; mt < 4; mt++) a[mt] = *(const v8s*)(Ab + mt * 16 * PADK + ks * 32);
        #pragma unroll
        for (int nt = 0; nt < 2; nt++) b[nt] = *(const v8s*)(Bb + nt * 16 * PADK + ks * 32);
        #pragma unroll
        for (int mt = 0; mt < 4; mt++)
            #pragma unroll
            for (int nt = 0; nt < 2; nt++)
                acc[mt][nt] = __builtin_amdgcn_mfma_f32_16x16x32_bf16(a[mt], b[nt], acc[mt][nt], 0, 0, 0);
    }

    int colbase = w * 32 + lm;        // wave-uniform fc/res split (w<2 -> fc)
    #pragma unroll
    for (int mt = 0; mt < 4; mt++) {
        #pragma unroll
        for (int nt = 0; nt < 2; nt++) {
            int col = colbase + nt * 16;
            #pragma unroll
            for (int p = 0; p < 4; p++) {
                int node = n0 + mt * 16 + lq * 4 + p;
                if (node < NN) {
                    float v = acc[mt][nt][p];
                    if (col < HD)
                        hops[((size_t)(r * 4) * NN + node) * HD + col] = v;
                    else
                        res[((size_t)r * NN + node) * HD + (col - HD)] = v;
                }
            }
        }
    }
}

// ---------------------------------------------------------------------------
// K1b: per-node attention scalars el/er. Thread per (r,n,h).
// ---------------------------------------------------------------------------
__global__ __launch_bounds__(256) void attn_node_kernel(
    const float* __restrict__ hops, const float* __restrict__ attn_l,
    const float* __restrict__ attn_r, float* __restrict__ el,
    float* __restrict__ er)
{
    int idx = blockIdx.x * 256 + threadIdx.x;
    if (idx >= RR * NN * HH) return;
    int h_ = idx & 1;
    int n = (idx >> 1) % NN;
    int r = idx / (NN * HH);
    const float4* x = (const float4*)(hops + ((size_t)(r * 4) * NN + n) * HD + h_ * DD);
    const float4* al = (const float4*)(attn_l + (r * HH + h_) * DD);
    const float4* ar = (const float4*)(attn_r + (r * HH + h_) * DD);
    float sl = 0.f, sr = 0.f;
    #pragma unroll
    for (int d = 0; d < 8; d++) {
        float4 v = x[d], a = al[d], b = ar[d];
        sl += v.x * a.x + v.y * a.y + v.z * a.z + v.w * a.w;
        sr += v.x * b.x + v.y * b.y + v.z * b.z + v.w * b.w;
    }
    el[idx] = sl;
    er[idx] = sr;
}

// ---------------------------------------------------------------------------
// K2: histogram of dst per relation
// ---------------------------------------------------------------------------
__global__ __launch_bounds__(256) void count_kernel(
    const int* __restrict__ dst, int* __restrict__ counts)
{
    int idx = blockIdx.x * 256 + threadIdx.x;
    if (idx >= RR * EE) return;
    int r = idx / EE;
    atomicAdd(&counts[r * NN + dst[idx]], 1);
}

// ---------------------------------------------------------------------------
// K3: per-relation exclusive scan, shuffle-based, 1024 elems/iter, 3 barriers.
// ---------------------------------------------------------------------------
__global__ __launch_bounds__(256) void scan_kernel(
    const int* __restrict__ counts, int* __restrict__ rowp,
    int* __restrict__ cursor)
{
    __shared__ int wsum[4];
    __shared__ int carry;
    int r = blockIdx.x;
    int tid = threadIdx.x;
    int lane = tid & 63, w = tid >> 6;
    if (tid == 0) { carry = 0; rowp[r * (NN + 1)] = 0; }
    __syncthreads();
    const int4* c4 = (const int4*)(counts + r * NN);
    int* rp = rowp + r * (NN + 1);
    int* cur = cursor + r * NN;
    for (int base = 0; base < NN / 4; base += 256) {
        int i4 = base + tid;
        int4 v = (i4 < NN / 4) ? c4[i4] : make_int4(0, 0, 0, 0);
        int s = v.x + v.y + v.z + v.w;
        int x = s;
        #pragma unroll
        for (int off = 1; off < 64; off <<= 1) {
            int t = __shfl_up(x, off, 64);
            if (lane >= off) x += t;
        }
        if (lane == 63) wsum[w] = x;
        __syncthreads();
        int add = carry;
        for (int j = 0; j < w; j++) add += wsum[j];
        int px = add + x - s;   // exclusive prefix for this thread's 4 elems
        if (i4 < NN / 4) {
            int e0 = i4 * 4;
            int p1 = px + v.x, p2 = p1 + v.y, p3 = p2 + v.z, p4 = p3 + v.w;
            cur[e0] = px;     rp[e0 + 1] = p1;
            cur[e0 + 1] = p1; rp[e0 + 2] = p2;
            cur[e0 + 2] = p2; rp[e0 + 3] = p3;
            cur[e0 + 3] = p3; rp[e0 + 4] = p4;
        }
        __syncthreads();
        if (tid == 255) carry += wsum[0] + wsum[1] + wsum[2] + wsum[3];
        __syncthreads();
    }
}

// ---------------------------------------------------------------------------
// K4: scatter edges into CSR slots; record = float4 {src_as_float, l0, l1, 0}
// ---------------------------------------------------------------------------
__global__ __launch_bounds__(256) void scatter_kernel(
    const int* __restrict__ src, const int* __restrict__ dst,
    const float* __restrict__ el, const float* __restrict__ er,
    int* __restrict__ cursor, float4* __restrict__ csrE)
{
    int idx = blockIdx.x * 256 + threadIdx.x;
    if (idx >= RR * EE) return;
    int r = idx / EE;
    int s = src[idx], d = dst[idx];
    float2 a = ((const float2*)el)[r * NN + s];
    float2 b = ((const float2*)er)[r * NN + d];
    float l0 = a.x + b.x;
    float l1 = a.y + b.y;
    l0 = l0 > 0.f ? l0 : NEG * l0;
    l1 = l1 > 0.f ? l1 : NEG * l1;
    int pos = atomicAdd(cursor + r * NN + d, 1);
    csrE[(size_t)r * EE + pos] = make_float4(__int_as_float(s), l0, l1, 0.f);
}

// ---------------------------------------------------------------------------
// K5: per-(dst,head) softmax stats in ONE pass: ndenom = {m0, m1, inv0, inv1}
// ---------------------------------------------------------------------------
__global__ __launch_bounds__(256) void alpha_kernel(
    const float4* __restrict__ csrE, const int* __restrict__ rowp,
    float4* __restrict__ ndenom)
{
    int idx = blockIdx.x * 256 + threadIdx.x;
    if (idx >= RR * NN) return;
    int r = idx / NN;
    int n = idx - r * NN;
    int b = rowp[r * (NN + 1) + n];
    int e = rowp[r * (NN + 1) + n + 1];
    if (e <= b) { ndenom[idx] = make_float4(0.f, 0.f, 0.f, 0.f); return; }
    const float4* E = csrE + (size_t)r * EE;
    float m0 = -1e30f, m1 = -1e30f, s0 = 0.f, s1 = 0.f;
    for (int i = b; i < e; i++) {
        float4 v = E[i];
        float nm0 = fmaxf(m0, v.y);
        float nm1 = fmaxf(m1, v.z);
        s0 = s0 * __expf(m0 - nm0) + __expf(v.y - nm0);
        s1 = s1 * __expf(m1 - nm1) + __expf(v.z - nm1);
        m0 = nm0; m1 = nm1;
    }
    ndenom[idx] = make_float4(m0, m1, 1.f / fmaxf(s0, 1e-9f), 1.f / fmaxf(s1, 1e-9f));
}

// ---------------------------------------------------------------------------
// K6: one diffusion hop. Wave per (r, dst); lane = feature element.
// alpha computed on the fly: exp(l - m); final scale by inv denom.
// ---------------------------------------------------------------------------
__global__ __launch_bounds__(256) void hop_kernel(
    float* __restrict__ hops, const float4* __restrict__ csrE,
    const int* __restrict__ rowp, const float4* __restrict__ ndenom, int k)
{
    int w = (blockIdx.x * 256 + threadIdx.x) >> 6;
    if (w >= RR * NN) return;
    int lane = threadIdx.x & 63;
    int hsel = lane >> 5;
    int r = w / NN;
    int n = w - r * NN;
    int b = rowp[r * (NN + 1) + n];
    int e = rowp[r * (NN + 1) + n + 1];
    float4 nd = ndenom[w];
    float m   = hsel ? nd.y : nd.x;
    float inv = hsel ? nd.w : nd.z;
    const float* hin = hops + (size_t)(r * 4 + k - 1) * NN * HD;
    const float4* E = csrE + (size_t)r * EE;
    float a0 = 0.f, a1 = 0.f, a2 = 0.f, a3 = 0.f;
    int i = b;
    for (; i + 3 < e; i += 4) {
        float4 e0 = E[i], e1 = E[i + 1], e2 = E[i + 2], e3 = E[i + 3];
        a0 += __expf((hsel ? e0.z : e0.y) - m) * hin[(size_t)__float_as_int(e0.x) * HD + lane];
        a1 += __expf((hsel ? e1.z : e1.y) - m) * hin[(size_t)__float_as_int(e1.x) * HD + lane];
        a2 += __expf((hsel ? e2.z : e2.y) - m) * hin[(size_t)__float_as_int(e2.x) * HD + lane];
        a3 += __expf((hsel ? e3.z : e3.y) - m) * hin[(size_t)__float_as_int(e3.x) * HD + lane];
    }
    for (; i < e; i++) {
        float4 e0 = E[i];
        a0 += __expf((hsel ? e0.z : e0.y) - m) * hin[(size_t)__float_as_int(e0.x) * HD + lane];
    }
    float acc = ((a0 + a1) + (a2 + a3)) * inv;
    hops[(size_t)(r * 4 + k) * NN * HD + (size_t)n * HD + lane] = acc;
}

// ---------------------------------------------------------------------------
// K7: hop-norm + hop attention + residual + relation combine + head mean.
// ---------------------------------------------------------------------------
__device__ __forceinline__ float red32(float v) {
    v += __shfl_xor(v, 16, 64);
    v += __shfl_xor(v, 8, 64);
    v += __shfl_xor(v, 4, 64);
    v += __shfl_xor(v, 2, 64);
    v += __shfl_xor(v, 1, 64);
    return v;
}

__global__ __launch_bounds__(256) void final_kernel(
    const float* __restrict__ hops, const float* __restrict__ res,
    const float* __restrict__ hal, const float* __restrict__ har,
    const float* __restrict__ w_rel, const float* __restrict__ b_rel,
    float* __restrict__ out)
{
    int w = (blockIdx.x * 256 + threadIdx.x) >> 6;
    if (w >= NN) return;
    int lane = threadIdx.x & 63;
    int h_ = lane >> 5;
    int d_ = lane & 31;
    float acc = 0.f;
    #pragma unroll
    for (int r = 0; r < RR; r++) {
        float wr = b_rel[r];
        #pragma unroll
        for (int j = 0; j < RR; j++) wr += w_rel[r * RR + j];
        float halv = hal[(r * HH + h_) * DD + d_];
        float harv = har[(r * HH + h_) * DD + d_];
        float vn[4], lg[4];
        float hr = 0.f;
        #pragma unroll
        for (int kk = 0; kk < 4; kk++) {
            float v = hops[((size_t)(r * 4 + kk) * NN + w) * HD + lane];
            float sq = red32(v * v);
            float inv = 1.f / fmaxf(sqrtf(sq), 1e-9f);
            v *= inv;
            vn[kk] = v;
            lg[kk] = red32(v * halv);
            if (kk == 0) hr = red32(v * harv);
        }
        float mx = -1e30f;
        #pragma unroll
        for (int kk = 0; kk < 4; kk++) {
            float l = lg[kk] + hr;
            l = l > 0.f ? l : NEG * l;
            lg[kk] = l;
            mx = fmaxf(mx, l);
        }
        float s = 0.f;
        #pragma unroll
        for (int kk = 0; kk < 4; kk++) { float ex = __expf(lg[kk] - mx); lg[kk] = ex; s += ex; }
        float o = 0.f;
        #pragma unroll
        for (int kk = 0; kk < 4; kk++) o += lg[kk] * vn[kk];
        o /= s;
        o += res[((size_t)r * NN + w) * HD + lane];
        acc += wr * o;
    }
    float other = __shfl_xor(acc, 32, 64);
    if (lane < 32) out[(size_t)w * DD + d_] = 0.5f * (acc + other);
}

// ---------------------------------------------------------------------------
extern "C" void kernel_launch(void* const* d_in, const int* in_sizes, int n_in,
                              void* d_out, int out_size, void* d_ws, size_t ws_size,
                              hipStream_t stream) {
    (void)in_sizes; (void)n_in; (void)out_size; (void)ws_size;
    const float* h     = (const float*)d_in[0];
    const int*   src   = (const int*)d_in[1];
    const int*   dst   = (const int*)d_in[2];
    const float* fcw   = (const float*)d_in[3];
    const float* resw  = (const float*)d_in[4];
    const float* atl   = (const float*)d_in[5];
    const float* atr   = (const float*)d_in[6];
    const float* hal   = (const float*)d_in[7];
    const float* har   = (const float*)d_in[8];
    const float* wrel  = (const float*)d_in[9];
    const float* brel  = (const float*)d_in[10];
    float* out = (float*)d_out;

    float* ws = (float*)d_ws;
    size_t off = 0;
    float* hops = ws + off;  off += (size_t)RR * 4 * NN * HD;       // 25.6M floats
    float* res  = ws + off;  off += (size_t)RR * NN * HD;           // 6.4M
    float* el   = ws + off;  off += (size_t)RR * NN * HH;
    float* er   = ws + off;  off += (size_t)RR * NN * HH;
    float4* csrE = (float4*)(ws + off);   off += (size_t)RR * EE * 4;
    float4* ndenom = (float4*)(ws + off); off += (size_t)RR * NN * 4;
    ushort* hb  = (ushort*)(ws + off);    off += (size_t)NN * IN / 2;
    ushort* wb  = (ushort*)(ws + off);    off += (size_t)RR * 128 * IN / 2;
    int* rowp   = (int*)(ws + off);  off += (size_t)RR * (NN + 1) + 3;
    int* cursor = (int*)(ws + off);  off += (size_t)RR * NN;
    int* counts = (int*)(ws + off);  off += (size_t)RR * NN;

    hipMemsetAsync(counts, 0, (size_t)RR * NN * sizeof(int), stream);

    cvt_h_kernel<<<(NN * IN / 4 + 255) / 256, 256, 0, stream>>>(h, hb);
    cvt_w_kernel<<<(RR * 128 * IN + 255) / 256, 256, 0, stream>>>(fcw, resw, wb);
    proj_mfma<<<313 * RR, 256, 0, stream>>>(hb, wb, hops, res);
    attn_node_kernel<<<(RR * NN * HH + 255) / 256, 256, 0, stream>>>(hops, atl, atr, el, er);
    count_kernel<<<(RR * EE + 255) / 256, 256, 0, stream>>>(dst, counts);
    scan_kernel<<<RR, 256, 0, stream>>>(counts, rowp, cursor);
    scatter_kernel<<<(RR * EE + 255) / 256, 256, 0, stream>>>(src, dst, el, er, cursor, csrE);
    alpha_kernel<<<(RR * NN + 255) / 256, 256, 0, stream>>>(csrE, rowp, ndenom);
    hop_kernel<<<(RR * NN) / 4, 256, 0, stream>>>(hops, csrE, rowp, ndenom, 1);
    hop_kernel<<<(RR * NN) / 4, 256, 0, stream>>>(hops, csrE, rowp, ndenom, 2);
    hop_kernel<<<(RR * NN) / 4, 256, 0, stream>>>(hops, csrE, rowp, ndenom, 3);
    final_kernel<<<NN / 4, 256, 0, stream>>>(hops, res, hal, har, wrel, brel, out);
}